// Round 6
// baseline (54.439 us; speedup 1.0000x reference)
//
#include <hip/hip_runtime.h>
#include <math.h>

// AttnRes: h[b,t,d] = sum_n softmax_n( rsqrt(mean_d V^2+eps) * dot(q*w, V[n,b,t,:]) ) * V[n,b,t,d]
//
// One 192-thread block per (b,t); 12 layer rows in registers; DPP wave
// reduction (VALU pipe); LDS combine + single barrier.
// Memory policy per R2/R4/R5 decomposition: TEMPORAL loads for the V stream
// (NT loads measured +6.1 us per 100% of the stream), NONTEMPORAL store for
// the output (no write-allocate: measured -9.3 us).

constexpr int NL = 12;
constexpr int D = 768;
constexpr int THREADS = 192;     // D/4 floats per thread
constexpr float EPS = 1e-6f;

typedef float f32x4 __attribute__((ext_vector_type(4)));

__device__ __forceinline__ void nt_store4(float* p, f32x4 v) {
    __builtin_nontemporal_store(v, reinterpret_cast<f32x4*>(p));
}

// --- DPP wave-64 sum reduction; total broadcast from lane 63 ---
template<int CTRL>
__device__ __forceinline__ float dpp_add(float x) {
    int y = __builtin_amdgcn_update_dpp(0, __builtin_bit_cast(int, x),
                                        CTRL, 0xf, 0xf, false);
    return x + __builtin_bit_cast(float, y);
}
__device__ __forceinline__ float wave_sum_uniform(float x) {
    x = dpp_add<0x111>(x);  // row_shr:1
    x = dpp_add<0x112>(x);  // row_shr:2
    x = dpp_add<0x114>(x);  // row_shr:4
    x = dpp_add<0x118>(x);  // row_shr:8
    x = dpp_add<0x142>(x);  // row_bcast:15
    x = dpp_add<0x143>(x);  // row_bcast:31 -> lane63 = wave total
    return __builtin_bit_cast(float,
        __builtin_amdgcn_readlane(__builtin_bit_cast(int, x), 63));
}

__global__ __launch_bounds__(THREADS)
void attnres_fused_kernel(const float* __restrict__ V,
                          const float* __restrict__ q,
                          const float* __restrict__ w,
                          float* __restrict__ out,
                          int BT)
{
    const int bt   = blockIdx.x;
    const int tid  = threadIdx.x;
    const int lane = tid & 63;
    const int wave = tid >> 6;          // 0..2

    const int d0 = tid * 4;
    float4 q4 = *reinterpret_cast<const float4*>(q + d0);
    float4 w4 = *reinterpret_cast<const float4*>(w + d0);
    const float qwx = q4.x * w4.x, qwy = q4.y * w4.y,
                qwz = q4.z * w4.z, qww = q4.w * w4.w;

    const size_t stride_n = (size_t)BT * (size_t)D;
    const float* base = V + (size_t)bt * (size_t)D + d0;

    // All 12 layer rows for this (b,t): coalesced temporal float4 loads.
    f32x4 v[NL];
    #pragma unroll
    for (int n = 0; n < NL; ++n)
        v[n] = *reinterpret_cast<const f32x4*>(base + (size_t)n * stride_n);

    // Per-thread partials: sum of squares, dot with q*w.
    float ss[NL], dq[NL];
    #pragma unroll
    for (int n = 0; n < NL; ++n) {
        const f32x4 x = v[n];
        ss[n] = x.x * x.x + x.y * x.y + x.z * x.z + x.w * x.w;
        dq[n] = qwx * x.x + qwy * x.y + qwz * x.z + qww * x.w;
    }

    // Wave reduction on the VALU pipe (DPP); wave-uniform results.
    float wred[2 * NL];
    #pragma unroll
    for (int n = 0; n < NL; ++n) {
        wred[n]      = wave_sum_uniform(ss[n]);
        wred[NL + n] = wave_sum_uniform(dq[n]);
    }

    // Cross-wave combine via LDS (6 float4 stores by lane 0, broadcast reads).
    __shared__ float red[3][2 * NL];
    if (lane == 0) {
        #pragma unroll
        for (int i = 0; i < 6; ++i)
            *reinterpret_cast<float4*>(&red[wave][i * 4]) =
                make_float4(wred[i * 4 + 0], wred[i * 4 + 1],
                            wred[i * 4 + 2], wred[i * 4 + 3]);
    }
    __syncthreads();

    float tot[2 * NL];
    #pragma unroll
    for (int i = 0; i < 6; ++i) {
        float4 a = *reinterpret_cast<const float4*>(&red[0][i * 4]);
        float4 b = *reinterpret_cast<const float4*>(&red[1][i * 4]);
        float4 c = *reinterpret_cast<const float4*>(&red[2][i * 4]);
        tot[i * 4 + 0] = a.x + b.x + c.x;
        tot[i * 4 + 1] = a.y + b.y + c.y;
        tot[i * 4 + 2] = a.z + b.z + c.z;
        tot[i * 4 + 3] = a.w + b.w + c.w;
    }

    // Softmax over the 12 layers (wave-uniform, cheap VALU).
    float lg[NL], mx = -3.0e38f;
    #pragma unroll
    for (int n = 0; n < NL; ++n) {
        const float inv_rms = rsqrtf(tot[n] * (1.0f / (float)D) + EPS);
        lg[n] = tot[NL + n] * inv_rms;
        mx = fmaxf(mx, lg[n]);
    }
    float al[NL], s = 0.0f;
    #pragma unroll
    for (int n = 0; n < NL; ++n) { al[n] = __expf(lg[n] - mx); s += al[n]; }
    const float inv = 1.0f / s;

    // Weighted sum over layers from registers.
    f32x4 h = {0.f, 0.f, 0.f, 0.f};
    #pragma unroll
    for (int n = 0; n < NL; ++n) {
        const float a = al[n] * inv;
        h.x += a * v[n].x;
        h.y += a * v[n].y;
        h.z += a * v[n].z;
        h.w += a * v[n].w;
    }

    nt_store4(out + (size_t)bt * (size_t)D + d0, h);
}

extern "C" void kernel_launch(void* const* d_in, const int* in_sizes, int n_in,
                              void* d_out, int out_size, void* d_ws, size_t ws_size,
                              hipStream_t stream)
{
    const float* V = (const float*)d_in[0];   // [N, B, T, D] fp32
    const float* q = (const float*)d_in[1];   // [D] fp32
    const float* w = (const float*)d_in[2];   // [D] fp32
    float* out = (float*)d_out;               // [B, T, D] fp32

    const int BT = out_size / D;              // B*T = 8192

    attnres_fused_kernel<<<dim3(BT), dim3(THREADS), 0, stream>>>(V, q, w, out, BT);
}

// Round 7
// 53.217 us; speedup vs baseline: 1.0230x; 1.0230x over previous
//
#include <hip/hip_runtime.h>
#include <math.h>

// AttnRes: h[b,t,d] = sum_n softmax_n( rsqrt(mean_d V^2+eps) * dot(q*w, V[n,b,t,:]) ) * V[n,b,t,d]
//
// FINAL (= R5 config, measured best 53.0 us ~= 98% of 6.29 TB/s copy ceiling):
// one 192-thread block per (b,t); 12 layer rows in registers; DPP wave
// reduction on the VALU pipe; LDS combine + single barrier.
// Memory policy (empirically tuned over R2/R4/R5/R6):
//   - layers 0..8 : temporal float4 loads
//   - layers 9..11: nontemporal loads
//   - output      : nontemporal store (no write-allocate; worth ~5-9 us)

constexpr int NL = 12;
constexpr int NL_TEMPORAL = 9;
constexpr int D = 768;
constexpr int THREADS = 192;     // D/4 floats per thread
constexpr float EPS = 1e-6f;

typedef float f32x4 __attribute__((ext_vector_type(4)));

__device__ __forceinline__ f32x4 nt_load4(const float* p) {
    return __builtin_nontemporal_load(reinterpret_cast<const f32x4*>(p));
}
__device__ __forceinline__ void nt_store4(float* p, f32x4 v) {
    __builtin_nontemporal_store(v, reinterpret_cast<f32x4*>(p));
}

// --- DPP wave-64 sum reduction; total broadcast from lane 63 ---
template<int CTRL>
__device__ __forceinline__ float dpp_add(float x) {
    int y = __builtin_amdgcn_update_dpp(0, __builtin_bit_cast(int, x),
                                        CTRL, 0xf, 0xf, false);
    return x + __builtin_bit_cast(float, y);
}
__device__ __forceinline__ float wave_sum_uniform(float x) {
    x = dpp_add<0x111>(x);  // row_shr:1
    x = dpp_add<0x112>(x);  // row_shr:2
    x = dpp_add<0x114>(x);  // row_shr:4
    x = dpp_add<0x118>(x);  // row_shr:8
    x = dpp_add<0x142>(x);  // row_bcast:15
    x = dpp_add<0x143>(x);  // row_bcast:31 -> lane63 = wave total
    return __builtin_bit_cast(float,
        __builtin_amdgcn_readlane(__builtin_bit_cast(int, x), 63));
}

__global__ __launch_bounds__(THREADS)
void attnres_fused_kernel(const float* __restrict__ V,
                          const float* __restrict__ q,
                          const float* __restrict__ w,
                          float* __restrict__ out,
                          int BT)
{
    const int bt   = blockIdx.x;
    const int tid  = threadIdx.x;
    const int lane = tid & 63;
    const int wave = tid >> 6;          // 0..2

    const int d0 = tid * 4;
    float4 q4 = *reinterpret_cast<const float4*>(q + d0);
    float4 w4 = *reinterpret_cast<const float4*>(w + d0);
    const float qwx = q4.x * w4.x, qwy = q4.y * w4.y,
                qwz = q4.z * w4.z, qww = q4.w * w4.w;

    const size_t stride_n = (size_t)BT * (size_t)D;
    const float* base = V + (size_t)bt * (size_t)D + d0;

    // 12 layer rows for this (b,t): 9 temporal + 3 nontemporal (tuned mix).
    f32x4 v[NL];
    #pragma unroll
    for (int n = 0; n < NL_TEMPORAL; ++n)
        v[n] = *reinterpret_cast<const f32x4*>(base + (size_t)n * stride_n);
    #pragma unroll
    for (int n = NL_TEMPORAL; n < NL; ++n)
        v[n] = nt_load4(base + (size_t)n * stride_n);

    // Per-thread partials: sum of squares, dot with q*w.
    float ss[NL], dq[NL];
    #pragma unroll
    for (int n = 0; n < NL; ++n) {
        const f32x4 x = v[n];
        ss[n] = x.x * x.x + x.y * x.y + x.z * x.z + x.w * x.w;
        dq[n] = qwx * x.x + qwy * x.y + qwz * x.z + qww * x.w;
    }

    // Wave reduction on the VALU pipe (DPP); wave-uniform results.
    float wred[2 * NL];
    #pragma unroll
    for (int n = 0; n < NL; ++n) {
        wred[n]      = wave_sum_uniform(ss[n]);
        wred[NL + n] = wave_sum_uniform(dq[n]);
    }

    // Cross-wave combine via LDS (6 float4 stores by lane 0, broadcast reads).
    __shared__ float red[3][2 * NL];
    if (lane == 0) {
        #pragma unroll
        for (int i = 0; i < 6; ++i)
            *reinterpret_cast<float4*>(&red[wave][i * 4]) =
                make_float4(wred[i * 4 + 0], wred[i * 4 + 1],
                            wred[i * 4 + 2], wred[i * 4 + 3]);
    }
    __syncthreads();

    float tot[2 * NL];
    #pragma unroll
    for (int i = 0; i < 6; ++i) {
        float4 a = *reinterpret_cast<const float4*>(&red[0][i * 4]);
        float4 b = *reinterpret_cast<const float4*>(&red[1][i * 4]);
        float4 c = *reinterpret_cast<const float4*>(&red[2][i * 4]);
        tot[i * 4 + 0] = a.x + b.x + c.x;
        tot[i * 4 + 1] = a.y + b.y + c.y;
        tot[i * 4 + 2] = a.z + b.z + c.z;
        tot[i * 4 + 3] = a.w + b.w + c.w;
    }

    // Softmax over the 12 layers (wave-uniform, cheap VALU).
    float lg[NL], mx = -3.0e38f;
    #pragma unroll
    for (int n = 0; n < NL; ++n) {
        const float inv_rms = rsqrtf(tot[n] * (1.0f / (float)D) + EPS);
        lg[n] = tot[NL + n] * inv_rms;
        mx = fmaxf(mx, lg[n]);
    }
    float al[NL], s = 0.0f;
    #pragma unroll
    for (int n = 0; n < NL; ++n) { al[n] = __expf(lg[n] - mx); s += al[n]; }
    const float inv = 1.0f / s;

    // Weighted sum over layers from registers.
    f32x4 h = {0.f, 0.f, 0.f, 0.f};
    #pragma unroll
    for (int n = 0; n < NL; ++n) {
        const float a = al[n] * inv;
        h.x += a * v[n].x;
        h.y += a * v[n].y;
        h.z += a * v[n].z;
        h.w += a * v[n].w;
    }

    nt_store4(out + (size_t)bt * (size_t)D + d0, h);
}

extern "C" void kernel_launch(void* const* d_in, const int* in_sizes, int n_in,
                              void* d_out, int out_size, void* d_ws, size_t ws_size,
                              hipStream_t stream)
{
    const float* V = (const float*)d_in[0];   // [N, B, T, D] fp32
    const float* q = (const float*)d_in[1];   // [D] fp32
    const float* w = (const float*)d_in[2];   // [D] fp32
    float* out = (float*)d_out;               // [B, T, D] fp32

    const int BT = out_size / D;              // B*T = 8192

    attnres_fused_kernel<<<dim3(BT), dim3(THREADS), 0, stream>>>(V, q, w, out, BT);
}